// Round 6
// baseline (578.979 us; speedup 1.0000x reference)
//
#include <hip/hip_runtime.h>
#include <hip/hip_fp16.h>

// Softmax attention (mask is a no-op). B=4, S=4096, D=256, fp32 in/out.
// Round 6: attn occupancy fix. r5 was 1 wave/SIMD (4-wave block, 147KB LDS):
// per-tile wall 13.8K cyc vs ~2.9K busy => latency-exposure-bound.
// New attn4: 512-thr blocks (8 waves x 32q = 256 q), split-K=4, grid 256
// (validated 1-block/CU flocking regime), LDS 128KB (K dbuf 64K + V single
// 32K + P 32K), VGPR<=256 via launch_bounds(512,2) by processing the 64-key
// tile as two 32-key halves (QK->SM->PV per half; P consumed before next
// rescale decision -- NOT the r2 staleness bug). All r5-validated fragment
// and swizzle math preserved verbatim.

typedef _Float16 f16x8 __attribute__((ext_vector_type(8)));
typedef _Float16 f16x4 __attribute__((ext_vector_type(4)));
typedef float    f32x4 __attribute__((ext_vector_type(4)));

#define MFMA16(A, B, C) __builtin_amdgcn_mfma_f32_16x16x32_f16((A), (B), (C), 0, 0, 0)

static __device__ __forceinline__ void gload16(const _Float16* g, _Float16* l) {
    __builtin_amdgcn_global_load_lds(
        (unsigned int __attribute__((address_space(1)))*)g,
        (unsigned int __attribute__((address_space(3)))*)l, 16, 0, 0);
}

// ---------------- kernel 0: convert x to fp16 hi/lo ----------------
__global__ __launch_bounds__(256) void convert_x_kernel(
    const float* __restrict__ x, _Float16* __restrict__ xh, _Float16* __restrict__ xl)
{
    int i = blockIdx.x * 256 + threadIdx.x;
    float4 v = ((const float4*)x)[i];
    float vv0 = v.x, vv1 = v.y, vv2 = v.z, vv3 = v.w;
    f16x4 h, l;
    _Float16 h0 = (_Float16)vv0; h[0] = h0; l[0] = (_Float16)(vv0 - (float)h0);
    _Float16 h1 = (_Float16)vv1; h[1] = h1; l[1] = (_Float16)(vv1 - (float)h1);
    _Float16 h2 = (_Float16)vv2; h[2] = h2; l[2] = (_Float16)(vv2 - (float)h2);
    _Float16 h3 = (_Float16)vv3; h[3] = h3; l[3] = (_Float16)(vv3 - (float)h3);
    ((f16x4*)xh)[i] = h;
    ((f16x4*)xl)[i] = l;
}

// ---------------- kernel 1: W -> W^T hi/lo fp16 ----------------
__global__ __launch_bounds__(256) void convert_w_kernel(
    const float* __restrict__ Wq, const float* __restrict__ Wk, const float* __restrict__ Wv,
    _Float16* __restrict__ Wth, _Float16* __restrict__ Wtl)
{
    int idx = blockIdx.x * 256 + threadIdx.x;
    int mat = idx >> 16, e = idx & 65535;
    int k = e >> 8, n = e & 255;
    const float* W = (mat == 0) ? Wq : (mat == 1) ? Wk : Wv;
    float v = W[e];
    _Float16 h = (_Float16)v;
    _Float16 lo = (_Float16)(v - (float)h);
    Wth[mat * 65536 + n * 256 + k] = h;
    Wtl[mat * 65536 + n * 256 + k] = lo;
}

// ---------------- kernel 2: projections (validated r1/r4/r5) ----------------
__global__ __launch_bounds__(256) void proj_kernel(
    const _Float16* __restrict__ xh, const _Float16* __restrict__ xl,
    const _Float16* __restrict__ Wth, const _Float16* __restrict__ Wtl,
    const float* __restrict__ bq, const float* __restrict__ bk, const float* __restrict__ bv,
    _Float16* __restrict__ Qf, _Float16* __restrict__ Kf, _Float16* __restrict__ Vt)
{
    const int mat = blockIdx.y;
    const int tid = threadIdx.x, wid = tid >> 6, lane = tid & 63;
    const int lrow = lane & 15, lgrp = lane >> 4;
    const int row0 = blockIdx.x * 64 + wid * 16;
    const _Float16* Wh = Wth + mat * 65536;
    const _Float16* Wl = Wtl + mat * 65536;
    const float* bias = (mat == 0) ? bq : (mat == 1) ? bk : bv;

    f32x4 acc[16];
#pragma unroll
    for (int i = 0; i < 16; ++i) acc[i] = f32x4{0.f, 0.f, 0.f, 0.f};

#pragma unroll
    for (int ks = 0; ks < 8; ++ks) {
        const int k0 = ks * 32 + lgrp * 8;
        f16x8 Ah = *(const f16x8*)(xh + (size_t)(row0 + lrow) * 256 + k0);
        f16x8 Al = *(const f16x8*)(xl + (size_t)(row0 + lrow) * 256 + k0);
#pragma unroll
        for (int nt = 0; nt < 16; ++nt) {
            const int n = nt * 16 + lrow;
            f16x8 Bh = *(const f16x8*)(Wh + n * 256 + k0);
            f16x8 Bl = *(const f16x8*)(Wl + n * 256 + k0);
            acc[nt] = MFMA16(Ah, Bh, acc[nt]);
            acc[nt] = MFMA16(Al, Bh, acc[nt]);
            acc[nt] = MFMA16(Ah, Bl, acc[nt]);
        }
    }

    const float LOG2E = 1.4426950408889634f;
#pragma unroll
    for (int nt = 0; nt < 16; ++nt) {
        const int n = nt * 16 + lrow;
        const float bb = bias[n];
        if (mat == 2) {
            const int m0 = row0 + lgrp * 4;
            f16x4 vv;
#pragma unroll
            for (int r = 0; r < 4; ++r) vv[r] = (_Float16)(acc[nt][r] + bb);
            *(f16x4*)(Vt + (size_t)n * 16384 + m0) = vv;
        } else {
            _Float16* dst = (mat == 0) ? Qf : Kf;
            const float s = (mat == 0) ? LOG2E : 1.0f;
#pragma unroll
            for (int r = 0; r < 4; ++r) {
                const int grow = row0 + lgrp * 4 + r;
                dst[(size_t)grow * 256 + n] = (_Float16)((acc[nt][r] + bb) * s);
            }
        }
    }
}

// ------- kernel 3: flash attention, 8 waves x 32q, tile=64, split-K=4 -------
__global__ __launch_bounds__(512, 2) void attn4_kernel(
    const _Float16* __restrict__ Qf, const _Float16* __restrict__ Kf,
    const _Float16* __restrict__ Vt, _Float16* __restrict__ Op01,
    _Float16* __restrict__ Op23, float* __restrict__ ml)
{
    __shared__ _Float16 Kb[2][64 * 256];   // [key][d], 512B rows, swizzled
    __shared__ _Float16 Vb[256 * 64];      // [d][key], 128B rows, 8-slot swz
    __shared__ _Float16 Pb[8][32 * 64];    // per-wave P [q][key], 128B rows

    const int tid = threadIdx.x, wid = tid >> 6, lane = tid & 63;
    const int lrow = lane & 15, lgrp = lane >> 4;

    // decode: XCD x hosts hw === x (mod 8); 2 groups per XCD, 16 q-blocks each
    const int hw = blockIdx.x;
    const int group = ((hw & 7) << 1) | (hw >> 7);   // [0,16)
    const int qi = (hw >> 3) & 15;                   // [0,16)
    const int b = group >> 2, split = group & 3;
    const size_t bS = (size_t)b * 4096;
    const size_t qrow = bS + qi * 256 + wid * 32;    // wave's first q row
    const size_t k0g = bS + (size_t)split * 1024;    // split's key base
    const int NT = 16;                               // 1024 keys / 64

    // Q resident: 32 q x 256 d per wave
    f16x8 Aq[2][8];
#pragma unroll
    for (int m = 0; m < 2; ++m)
#pragma unroll
        for (int ks = 0; ks < 8; ++ks)
            Aq[m][ks] = *(const f16x8*)(Qf + (qrow + m * 16 + lrow) * 256 + ks * 32 + lgrp * 8);

    f32x4 Oacc[2][16];
#pragma unroll
    for (int m = 0; m < 2; ++m)
#pragma unroll
        for (int i = 0; i < 16; ++i) Oacc[m][i] = f32x4{0.f, 0.f, 0.f, 0.f};
    float m_r[2][4], l_r[2][4];
#pragma unroll
    for (int m = 0; m < 2; ++m)
#pragma unroll
        for (int r = 0; r < 4; ++r) { m_r[m][r] = -1e30f; l_r[m][r] = 0.f; }

    _Float16* Pw = Pb[wid];

    auto stage_K = [&](int buf, int t) {
        const size_t krow = k0g + (size_t)t * 64;
#pragma unroll
        for (int it = 0; it < 4; ++it) {   // 2048 x 16B slots / 512 thr
            const int s = it * 512 + tid;
            const int row = s >> 5, c16 = s & 31;
            gload16(Kf + (krow + row) * 256 + ((c16 ^ (row & 7)) * 8), &Kb[buf][s * 8]);
        }
    };
    auto stage_V = [&](int t) {
        const size_t krow = k0g + (size_t)t * 64;
#pragma unroll
        for (int it = 0; it < 4; ++it) {   // 2048 x 16B slots / 512 thr
            const int s = it * 512 + tid;
            const int d = s >> 3, c8 = s & 7;
            gload16(Vt + (size_t)d * 16384 + krow + ((c8 ^ (d & 7)) * 8), &Vb[s * 8]);
        }
    };

    stage_K(0, 0);
    asm volatile("s_waitcnt vmcnt(0)" ::: "memory");
    __builtin_amdgcn_s_barrier();

    const float THR = 10.0f;   // defer-max threshold (log2 domain)
    int buf = 0;
    for (int t = 0; t < NT; ++t) {
        stage_V(t);                          // into single V buffer
        if (t + 1 < NT) stage_K(buf ^ 1, t + 1);
        const _Float16* K_ = Kb[buf];

#pragma unroll
        for (int h = 0; h < 2; ++h) {        // two 32-key halves
            // ---- QK half: 32q x 32k ----
            f32x4 sc[2][2];                  // [chunk][m]
#pragma unroll
            for (int c = 0; c < 2; ++c) {
                sc[c][0] = f32x4{0.f, 0.f, 0.f, 0.f};
                sc[c][1] = f32x4{0.f, 0.f, 0.f, 0.f};
                const int key = (h * 2 + c) * 16 + lrow;
#pragma unroll
                for (int ks = 0; ks < 8; ++ks) {
                    f16x8 Bk = *(const f16x8*)(K_ + key * 256 + (((ks * 4 + lgrp) ^ (key & 7)) * 8));
                    sc[c][0] = MFMA16(Aq[0][ks], Bk, sc[c][0]);
                    sc[c][1] = MFMA16(Aq[1][ks], Bk, sc[c][1]);
                }
            }
            // ---- half-wide rescale decision ----
            bool ok = true;
            float mxt[2][4];
#pragma unroll
            for (int m = 0; m < 2; ++m)
#pragma unroll
                for (int r = 0; r < 4; ++r) {
                    float v = fmaxf(sc[0][m][r], sc[1][m][r]);
#pragma unroll
                    for (int off = 8; off > 0; off >>= 1) v = fmaxf(v, __shfl_xor(v, off));
                    mxt[m][r] = v;
                    ok = ok && (v <= m_r[m][r] + THR);
                }
            if (!__all(ok)) {
#pragma unroll
                for (int m = 0; m < 2; ++m)
#pragma unroll
                    for (int r = 0; r < 4; ++r) {
                        const float mn = fmaxf(m_r[m][r], mxt[m][r]);
                        const float scl = exp2f(m_r[m][r] - mn);
                        m_r[m][r] = mn;
                        l_r[m][r] *= scl;
#pragma unroll
                        for (int nt2 = 0; nt2 < 16; ++nt2) Oacc[m][nt2][r] *= scl;
                    }
            }
            // ---- P = exp2(sc - m_r) for this half ----
#pragma unroll
            for (int m = 0; m < 2; ++m)
#pragma unroll
                for (int r = 0; r < 4; ++r) {
                    const int q = m * 16 + lgrp * 4 + r;
                    const int qx = (q & 7) << 4;
                    const float p0 = exp2f(sc[0][m][r] - m_r[m][r]);
                    const float p1 = exp2f(sc[1][m][r] - m_r[m][r]);
                    *(_Float16*)((char*)Pw + q * 128 + (((h * 2 + 0) * 32 + lrow * 2) ^ qx)) = (_Float16)p0;
                    *(_Float16*)((char*)Pw + q * 128 + (((h * 2 + 1) * 32 + lrow * 2) ^ qx)) = (_Float16)p1;
                    float rs = p0 + p1;
#pragma unroll
                    for (int off = 8; off > 0; off >>= 1) rs += __shfl_xor(rs, off);
                    l_r[m][r] += rs;
                }

            if (h == 0) {
                // V(t) + K(t+1) landed; all waves synced; P(A) drained
                asm volatile("s_waitcnt vmcnt(0) lgkmcnt(0)" ::: "memory");
                __builtin_amdgcn_s_barrier();
                __builtin_amdgcn_sched_barrier(0);
            } else {
                asm volatile("s_waitcnt lgkmcnt(0)" ::: "memory");
                __builtin_amdgcn_sched_barrier(0);
            }

            // ---- PV half: O[32q x 256d] += P_h * V[h*32..] ----
            f16x8 Ap[2];
#pragma unroll
            for (int m = 0; m < 2; ++m) {
                const int q2 = m * 16 + lrow;
                Ap[m] = *(const f16x8*)((const char*)Pw + q2 * 128 +
                         ((h * 64 + lgrp * 16) ^ ((q2 & 7) << 4)));
            }
            __builtin_amdgcn_s_setprio(1);
#pragma unroll
            for (int nt = 0; nt < 16; ++nt) {
                const int d = nt * 16 + lrow;
                f16x8 Bv = *(const f16x8*)(Vb + d * 64 + (((h * 4 + lgrp) ^ (d & 7)) * 8));
                Oacc[0][nt] = MFMA16(Ap[0], Bv, Oacc[0][nt]);
                Oacc[1][nt] = MFMA16(Ap[1], Bv, Oacc[1][nt]);
            }
            __builtin_amdgcn_s_setprio(0);
        }

        __builtin_amdgcn_s_barrier();   // V + K[buf] free for next iteration
        buf ^= 1;
    }

    // ---- epilogue: normalized fp16 partial + (m, l) ----
    _Float16* Ops = (split < 2) ? (Op01 + (size_t)split * 4194304)
                                : (Op23 + (size_t)(split - 2) * 4194304);
#pragma unroll
    for (int m = 0; m < 2; ++m)
#pragma unroll
        for (int r = 0; r < 4; ++r) {
            const float inv = 1.0f / l_r[m][r];
            const size_t grow = qrow + m * 16 + lgrp * 4 + r;
#pragma unroll
            for (int nt = 0; nt < 16; ++nt) {
                const int d = nt * 16 + lrow;
                Ops[grow * 256 + d] = (_Float16)(Oacc[m][nt][r] * inv);
            }
            if (lrow == 0) {
                ml[((size_t)split * 16384 + grow) * 2]     = m_r[m][r];
                ml[((size_t)split * 16384 + grow) * 2 + 1] = l_r[m][r];
            }
        }
}

// ---------------- kernel 4: combine split-K partials (NS=4, r4-validated) ----
__global__ __launch_bounds__(256) void combine_kernel(
    const _Float16* __restrict__ Op01, const _Float16* __restrict__ Op23,
    const float* __restrict__ ml, float* __restrict__ out)
{
    const int idx = blockIdx.x * 256 + threadIdx.x;
    const int row = idx >> 2, dq = (idx & 3) * 64;
    float m_s[4], l_s[4], w[4];
    float M = -1e30f;
#pragma unroll
    for (int s = 0; s < 4; ++s) {
        m_s[s] = ml[((size_t)s * 16384 + row) * 2];
        l_s[s] = ml[((size_t)s * 16384 + row) * 2 + 1];
        M = fmaxf(M, m_s[s]);
    }
    float Wsum = 0.f;
#pragma unroll
    for (int s = 0; s < 4; ++s) { w[s] = l_s[s] * exp2f(m_s[s] - M); Wsum += w[s]; }
    const float inv = 1.0f / Wsum;
#pragma unroll
    for (int s = 0; s < 4; ++s) w[s] *= inv;

#pragma unroll
    for (int ch = 0; ch < 8; ++ch) {
        const int d0 = dq + ch * 8;
        float acc[8] = {0.f, 0.f, 0.f, 0.f, 0.f, 0.f, 0.f, 0.f};
#pragma unroll
        for (int s = 0; s < 4; ++s) {
            const _Float16* Op = (s < 2) ? (Op01 + (size_t)s * 4194304)
                                         : (Op23 + (size_t)(s - 2) * 4194304);
            f16x8 v = *(const f16x8*)(Op + (size_t)row * 256 + d0);
#pragma unroll
            for (int j = 0; j < 8; ++j) acc[j] += w[s] * (float)v[j];
        }
        float4 o0 = {acc[0], acc[1], acc[2], acc[3]};
        float4 o1 = {acc[4], acc[5], acc[6], acc[7]};
        *(float4*)(out + (size_t)row * 256 + d0) = o0;
        *(float4*)(out + (size_t)row * 256 + d0 + 4) = o1;
    }
}

extern "C" void kernel_launch(void* const* d_in, const int* in_sizes, int n_in,
                              void* d_out, int out_size, void* d_ws, size_t ws_size,
                              hipStream_t stream) {
    const float* x  = (const float*)d_in[0];
    const float* Wq = (const float*)d_in[1];
    const float* bq = (const float*)d_in[2];
    const float* Wk = (const float*)d_in[3];
    const float* bk = (const float*)d_in[4];
    const float* Wv = (const float*)d_in[5];
    const float* bv = (const float*)d_in[6];
    float* out = (float*)d_out;

    // ws: xh/xl (reused as Op splits 0/1) | Qf | Kf | Vt | W | ml | Op23
    _Float16* xh  = (_Float16*)d_ws;
    _Float16* xl  = xh  + 4194304;
    _Float16* Qf  = xl  + 4194304;
    _Float16* Kf  = Qf  + 4194304;
    _Float16* Vt  = Kf  + 4194304;
    _Float16* Wth = Vt  + 4194304;
    _Float16* Wtl = Wth + 196608;
    float*    ml  = (float*)(Wtl + 196608);            // 4*16384*2 f32
    _Float16* Op23 = (_Float16*)((char*)ml + 524288);  // splits 2,3 (16MB)

    convert_x_kernel<<<4096, 256, 0, stream>>>(x, xh, xl);
    convert_w_kernel<<<768, 256, 0, stream>>>(Wq, Wk, Wv, Wth, Wtl);
    proj_kernel<<<dim3(256, 3), 256, 0, stream>>>(xh, xl, Wth, Wtl, bq, bk, bv, Qf, Kf, Vt);
    attn4_kernel<<<256, 512, 0, stream>>>(Qf, Kf, Vt, xh, Op23, ml);
    combine_kernel<<<256, 256, 0, stream>>>(xh, Op23, ml, out);
}

// Round 7
// 214.743 us; speedup vs baseline: 2.6961x; 2.6961x over previous
//
#include <hip/hip_runtime.h>
#include <hip/hip_fp16.h>

// Softmax attention (mask is a no-op). B=4, S=4096, D=256, fp32 in/out.
// Round 7:
//  (a) attn5: swapped-operand 32x32 MFMA flash in the r5-VALIDATED dispatch
//      regime (grid 256 x 256thr, 1 block/CU, group=hw&7). S^T = K.Q^T and
//      O^T = V^T.P put q in the C COLUMN for both => per-lane m/l, in-register
//      softmax (1 shfl per reduce), P->PV frags via pack+shfl_xor(32), no P LDS.
//  (b) proj fix: convert kernels emit x and W in FRAGMENT-LINEAR layout so
//      proj's A/B loads are coalesced 1KB wave reads (was a 16-line gather,
//      ~115us). Epilogues unchanged (r5 regime had exact WRITE_SIZE).

typedef _Float16 f16x8 __attribute__((ext_vector_type(8)));
typedef _Float16 f16x4 __attribute__((ext_vector_type(4)));
typedef float    f32x4 __attribute__((ext_vector_type(4)));
typedef float    f32x16 __attribute__((ext_vector_type(16)));

#define MFMA16(A, B, C) __builtin_amdgcn_mfma_f32_16x16x32_f16((A), (B), (C), 0, 0, 0)
#define MFMA32(A, B, C) __builtin_amdgcn_mfma_f32_32x32x16_f16((A), (B), (C), 0, 0, 0)

static __device__ __forceinline__ void gload16(const _Float16* g, _Float16* l) {
    __builtin_amdgcn_global_load_lds(
        (unsigned int __attribute__((address_space(1)))*)g,
        (unsigned int __attribute__((address_space(3)))*)l, 16, 0, 0);
}

static __device__ __forceinline__ unsigned packh(float a, float b) {
    union { _Float16 h[2]; unsigned u; } x;
    x.h[0] = (_Float16)a; x.h[1] = (_Float16)b;
    return x.u;
}

// ---------------- kernel 0: x -> fp16 hi/lo in FRAGMENT-LINEAR layout -------
// x2[rowblk][ks][lane][8]: lane = (row&15) + 16*((k>>3)&3), elem = k&7.
__global__ __launch_bounds__(256) void convert_x_kernel(
    const float* __restrict__ x, _Float16* __restrict__ xh, _Float16* __restrict__ xl)
{
    int i = blockIdx.x * 256 + threadIdx.x;     // float4 index
    int e = i * 4;
    int row = e >> 8, k = e & 255;              // k % 4 == 0
    float4 v = ((const float4*)x)[i];
    float vv[4] = {v.x, v.y, v.z, v.w};
    f16x4 h, l;
#pragma unroll
    for (int j = 0; j < 4; ++j) {
        _Float16 hh = (_Float16)vv[j];
        h[j] = hh; l[j] = (_Float16)(vv[j] - (float)hh);
    }
    const int lane = (row & 15) + 16 * ((k >> 3) & 3);
    const int dst = (((row >> 4) * 8 + (k >> 5)) * 64 + lane) * 8 + (k & 7);
    *(f16x4*)(xh + dst) = h;
    *(f16x4*)(xl + dst) = l;
}

// ---------------- kernel 1: W -> W^T hi/lo in FRAGMENT-LINEAR layout --------
// W2[mat][ks][nt][lane][8]: lane = (n&15) + 16*((k>>3)&3), elem = k&7.
__global__ __launch_bounds__(256) void convert_w_kernel(
    const float* __restrict__ Wq, const float* __restrict__ Wk, const float* __restrict__ Wv,
    _Float16* __restrict__ Wth, _Float16* __restrict__ Wtl)
{
    int idx = blockIdx.x * 256 + threadIdx.x;
    int mat = idx >> 16, e = idx & 65535;
    int k = e >> 8, n = e & 255;                // W row-major [k][n]
    const float* W = (mat == 0) ? Wq : (mat == 1) ? Wk : Wv;
    float v = W[e];
    _Float16 h = (_Float16)v;
    _Float16 lo = (_Float16)(v - (float)h);
    const int lane = (n & 15) + 16 * ((k >> 3) & 3);
    const int dst = mat * 65536 + (((k >> 5) * 16 + (n >> 4)) * 64 + lane) * 8 + (k & 7);
    Wth[dst] = h;
    Wtl[dst] = lo;
}

// ---------------- kernel 2: projections, coalesced fragment loads -----------
__global__ __launch_bounds__(256) void proj_kernel(
    const _Float16* __restrict__ xh, const _Float16* __restrict__ xl,
    const _Float16* __restrict__ Wth, const _Float16* __restrict__ Wtl,
    const float* __restrict__ bq, const float* __restrict__ bk, const float* __restrict__ bv,
    _Float16* __restrict__ Qf, _Float16* __restrict__ Kf, _Float16* __restrict__ Vt)
{
    const int mat = blockIdx.y;
    const int tid = threadIdx.x, wid = tid >> 6, lane = tid & 63;
    const int lrow = lane & 15, lgrp = lane >> 4;
    const int rb = blockIdx.x * 4 + wid;        // rowblock of 16
    const int row0 = rb * 16;
    const _Float16* Wh = Wth + mat * 65536;
    const _Float16* Wl = Wtl + mat * 65536;
    const float* bias = (mat == 0) ? bq : (mat == 1) ? bk : bv;

    f32x4 acc[16];
#pragma unroll
    for (int i = 0; i < 16; ++i) acc[i] = f32x4{0.f, 0.f, 0.f, 0.f};

#pragma unroll
    for (int ks = 0; ks < 8; ++ks) {
        const size_t abase = (((size_t)rb * 8 + ks) * 64 + lane) * 8;
        f16x8 Ah = *(const f16x8*)(xh + abase);
        f16x8 Al = *(const f16x8*)(xl + abase);
#pragma unroll
        for (int nt = 0; nt < 16; ++nt) {
            const size_t bbase = ((ks * 16 + nt) * 64 + lane) * 8;
            f16x8 Bh = *(const f16x8*)(Wh + bbase);
            f16x8 Bl = *(const f16x8*)(Wl + bbase);
            acc[nt] = MFMA16(Ah, Bh, acc[nt]);
            acc[nt] = MFMA16(Al, Bh, acc[nt]);
            acc[nt] = MFMA16(Ah, Bl, acc[nt]);
        }
    }

    const float LOG2E = 1.4426950408889634f;
#pragma unroll
    for (int nt = 0; nt < 16; ++nt) {
        const int n = nt * 16 + lrow;
        const float bb = bias[n];
        if (mat == 2) {
            const int m0 = row0 + lgrp * 4;
            f16x4 vv;
#pragma unroll
            for (int r = 0; r < 4; ++r) vv[r] = (_Float16)(acc[nt][r] + bb);
            *(f16x4*)(Vt + (size_t)n * 16384 + m0) = vv;
        } else {
            _Float16* dst = (mat == 0) ? Qf : Kf;
            const float s = (mat == 0) ? LOG2E : 1.0f;
#pragma unroll
            for (int r = 0; r < 4; ++r) {
                const int grow = row0 + lgrp * 4 + r;
                dst[(size_t)grow * 256 + n] = (_Float16)((acc[nt][r] + bb) * s);
            }
        }
    }
}

// -------- kernel 3: attn5 — swapped 32x32, in-register softmax --------------
// grid 256 x 256thr (r5 regime). 4 waves x 32q = 128 q/block, KV tile 64,
// split-K=2. S^T=K.Q^T: C col = q = lane&31. O^T=V^T.P: C col = q too.
// LDS: K dbuf 64KB (5-bit XOR swz) + V dbuf 64KB (3-bit XOR swz) = 128KB.
__global__ __launch_bounds__(256) void attn5_kernel(
    const _Float16* __restrict__ Qf, const _Float16* __restrict__ Kf,
    const _Float16* __restrict__ Vt, _Float16* __restrict__ Op,
    float* __restrict__ ml)
{
    __shared__ _Float16 Kb[2][64 * 256];   // [key][d], 512B rows
    __shared__ _Float16 Vb[2][256 * 64];   // [d][key], 128B rows

    const int tid = threadIdx.x, wid = tid >> 6, lane = tid & 63;
    const int lq = lane & 31, hi = lane >> 5;

    const int hw = blockIdx.x;
    const int group = hw & 7;              // XCD under 1-block/CU round-robin
    const int qi = hw >> 3;                // [0,32)
    const int b = group >> 1, split = group & 1;
    const size_t bS = (size_t)b * 4096;
    const size_t qrow = bS + qi * 128 + wid * 32;
    const size_t k0g = bS + (size_t)split * 2048;
    const int NT = 32;

    // Q as B-fragments: lane holds Q[q=lq][d = ks*16 + hi*8 .. +8]
    f16x8 QB[16];
#pragma unroll
    for (int ks = 0; ks < 16; ++ks)
        QB[ks] = *(const f16x8*)(Qf + (qrow + lq) * 256 + ks * 16 + hi * 8);

    f32x16 Oacc[8];
#pragma unroll
    for (int i = 0; i < 8; ++i)
#pragma unroll
        for (int r = 0; r < 16; ++r) Oacc[i][r] = 0.f;
    float m_r = -1e30f, l_r = 0.f;

    auto stage = [&](int buf, int t) {
        const size_t krow = k0g + (size_t)t * 64;
#pragma unroll
        for (int it = 0; it < 8; ++it) {   // K: 2048 slots, 5-bit XOR swz src
            const int s = it * 256 + tid;
            const int row = s >> 5, c = s & 31;
            const int src = c ^ (row & 7) ^ (((row >> 3) & 3) << 3);
            gload16(Kf + (krow + row) * 256 + src * 8, &Kb[buf][s * 8]);
        }
#pragma unroll
        for (int it = 0; it < 8; ++it) {   // V^T: 2048 slots, 3-bit XOR swz
            const int s = it * 256 + tid;
            const int d = s >> 3, c = s & 7;
            gload16(Vt + (size_t)d * 16384 + krow + ((c ^ (d & 7)) * 8), &Vb[buf][s * 8]);
        }
    };

    stage(0, 0);
    asm volatile("s_waitcnt vmcnt(0)" ::: "memory");
    __builtin_amdgcn_s_barrier();

    const float THR = 10.0f;
    const int kx = (lq & 7) ^ (((lq >> 3) & 3) << 3);   // K-read slot XOR
    int buf = 0;
    for (int t = 0; t < NT; ++t) {
        if (t + 1 < NT) stage(buf ^ 1, t + 1);
        const _Float16* K_ = Kb[buf];
        const _Float16* V_ = Vb[buf];

        // ---- QK: sc[kb] = C[key_local][q], col q = lq ----
        f32x16 sc[2];
#pragma unroll
        for (int kb = 0; kb < 2; ++kb) {
#pragma unroll
            for (int r = 0; r < 16; ++r) sc[kb][r] = 0.f;
#pragma unroll
            for (int ks = 0; ks < 16; ++ks) {
                const int slot = (2 * ks + hi) ^ kx;
                f16x8 Ak = *(const f16x8*)((const char*)K_ + (kb * 32 + lq) * 512 + slot * 16);
                sc[kb] = MFMA32(Ak, QB[ks], sc[kb]);
            }
        }

        // ---- per-lane online softmax (lane owns q = lq) ----
        float mx = sc[0][0];
#pragma unroll
        for (int r = 1; r < 16; ++r) mx = fmaxf(mx, sc[0][r]);
#pragma unroll
        for (int r = 0; r < 16; ++r) mx = fmaxf(mx, sc[1][r]);
        mx = fmaxf(mx, __shfl_xor(mx, 32));
        if (__any(mx > m_r + THR)) {
            const float mn = fmaxf(m_r, mx);
            const float scl = exp2f(m_r - mn);
            m_r = mn; l_r *= scl;
#pragma unroll
            for (int i = 0; i < 8; ++i)
#pragma unroll
                for (int r = 0; r < 16; ++r) Oacc[i][r] *= scl;
        }

        // ---- P = exp2(sc - m_r); build PV B-frags via pack + shfl ----
        float p[32]; float rs = 0.f;
#pragma unroll
        for (int r = 0; r < 16; ++r) { p[r] = exp2f(sc[0][r] - m_r); rs += p[r]; }
#pragma unroll
        for (int r = 0; r < 16; ++r) { p[16 + r] = exp2f(sc[1][r] - m_r); rs += p[16 + r]; }
        l_r += rs + __shfl_xor(rs, 32);

        f16x8 Pfrag[4];
#pragma unroll
        for (int kb = 0; kb < 2; ++kb) {
            unsigned w[8], pw[8];
#pragma unroll
            for (int j = 0; j < 8; ++j) {
                w[j] = packh(p[kb * 16 + 2 * j], p[kb * 16 + 2 * j + 1]);
                pw[j] = __shfl_xor(w[j], 32);
            }
#pragma unroll
            for (int s = 0; s < 2; ++s) {
                // frag keys: kstep*16 + hi*8 .. +8; lower 4 from hl=0 words,
                // upper 4 from hl=1 words, at word idx 4s+2*hi (consumer hi).
                unsigned f0 = hi ? pw[4 * s + 2] : w[4 * s + 0];
                unsigned f1 = hi ? pw[4 * s + 3] : w[4 * s + 1];
                unsigned f2 = hi ? w[4 * s + 2] : pw[4 * s + 0];
                unsigned f3 = hi ? w[4 * s + 3] : pw[4 * s + 1];
                union { unsigned u[4]; f16x8 f; } cvt;
                cvt.u[0] = f0; cvt.u[1] = f1; cvt.u[2] = f2; cvt.u[3] = f3;
                Pfrag[kb * 2 + s] = cvt.f;
            }
        }

        // ---- PV: O^T[d][q] += V^T.P ; A = V^T frag, B = Pfrag ----
#pragma unroll
        for (int dblk = 0; dblk < 8; ++dblk) {
#pragma unroll
            for (int kstep = 0; kstep < 4; ++kstep) {
                const int slot = (kstep * 2 + hi) ^ (lq & 7);
                f16x8 Av = *(const f16x8*)((const char*)V_ + (dblk * 32 + lq) * 128 + slot * 16);
                Oacc[dblk] = MFMA32(Av, Pfrag[kstep], Oacc[dblk]);
            }
        }

        asm volatile("s_waitcnt vmcnt(0)" ::: "memory");
        __builtin_amdgcn_s_barrier();
        buf ^= 1;
    }

    // ---- epilogue: lane owns q = qrow + lq; d = dblk*32 + 8*quad + 4*hi + j
    _Float16* Ops = Op + (size_t)split * 4194304;
    const float inv = 1.0f / l_r;
    const size_t grow = qrow + lq;
#pragma unroll
    for (int dblk = 0; dblk < 8; ++dblk)
#pragma unroll
        for (int quad = 0; quad < 4; ++quad) {
            f16x4 o;
#pragma unroll
            for (int j = 0; j < 4; ++j) o[j] = (_Float16)(Oacc[dblk][quad * 4 + j] * inv);
            *(f16x4*)(Ops + grow * 256 + dblk * 32 + 8 * quad + 4 * hi) = o;
        }
    if (hi == 0) {
        ml[((size_t)split * 16384 + grow) * 2]     = m_r;
        ml[((size_t)split * 16384 + grow) * 2 + 1] = l_r;
    }
}

// ---------------- kernel 4: combine split-K partials (NS=2, r5-validated) ---
__global__ __launch_bounds__(256) void combine_kernel(
    const _Float16* __restrict__ Op, const float* __restrict__ ml,
    float* __restrict__ out)
{
    const int idx = blockIdx.x * 256 + threadIdx.x;
    const int row = idx >> 2, dq = (idx & 3) * 64;
    float m_s[2], l_s[2], w[2];
    float M = -1e30f;
#pragma unroll
    for (int s = 0; s < 2; ++s) {
        m_s[s] = ml[((size_t)s * 16384 + row) * 2];
        l_s[s] = ml[((size_t)s * 16384 + row) * 2 + 1];
        M = fmaxf(M, m_s[s]);
    }
    float Wsum = 0.f;
#pragma unroll
    for (int s = 0; s < 2; ++s) { w[s] = l_s[s] * exp2f(m_s[s] - M); Wsum += w[s]; }
    const float inv = 1.0f / Wsum;
#pragma unroll
    for (int s = 0; s < 2; ++s) w[s] *= inv;

#pragma unroll
    for (int ch = 0; ch < 8; ++ch) {
        const int d0 = dq + ch * 8;
        float acc[8] = {0.f, 0.f, 0.f, 0.f, 0.f, 0.f, 0.f, 0.f};
#pragma unroll
        for (int s = 0; s < 2; ++s) {
            f16x8 v = *(const f16x8*)(Op + (size_t)s * 4194304 + (size_t)row * 256 + d0);
#pragma unroll
            for (int j = 0; j < 8; ++j) acc[j] += w[s] * (float)v[j];
        }
        float4 o0 = {acc[0], acc[1], acc[2], acc[3]};
        float4 o1 = {acc[4], acc[5], acc[6], acc[7]};
        *(float4*)(out + (size_t)row * 256 + d0) = o0;
        *(float4*)(out + (size_t)row * 256 + d0 + 4) = o1;
    }
}

extern "C" void kernel_launch(void* const* d_in, const int* in_sizes, int n_in,
                              void* d_out, int out_size, void* d_ws, size_t ws_size,
                              hipStream_t stream) {
    const float* x  = (const float*)d_in[0];
    const float* Wq = (const float*)d_in[1];
    const float* bq = (const float*)d_in[2];
    const float* Wk = (const float*)d_in[3];
    const float* bk = (const float*)d_in[4];
    const float* Wv = (const float*)d_in[5];
    const float* bv = (const float*)d_in[6];
    float* out = (float*)d_out;

    // ws: xh2/xl2 (reused as Op splits 0/1) | Qf | Kf | Vt | W2 | ml
    _Float16* xh  = (_Float16*)d_ws;
    _Float16* xl  = xh  + 4194304;
    _Float16* Qf  = xl  + 4194304;
    _Float16* Kf  = Qf  + 4194304;
    _Float16* Vt  = Kf  + 4194304;
    _Float16* Wth = Vt  + 4194304;
    _Float16* Wtl = Wth + 196608;
    float*    ml  = (float*)(Wtl + 196608);   // 2*16384*2 f32 = 256KB

    convert_x_kernel<<<4096, 256, 0, stream>>>(x, xh, xl);
    convert_w_kernel<<<768, 256, 0, stream>>>(Wq, Wk, Wv, Wth, Wtl);
    proj_kernel<<<dim3(256, 3), 256, 0, stream>>>(xh, xl, Wth, Wtl, bq, bk, bv, Qf, Kf, Vt);
    attn5_kernel<<<256, 256, 0, stream>>>(Qf, Kf, Vt, xh, ml);   // Op = xh/xl
    combine_kernel<<<256, 256, 0, stream>>>(xh, ml, out);
}